// Round 4
// baseline (748.907 us; speedup 1.0000x reference)
//
#include <hip/hip_runtime.h>

typedef unsigned short u16;
typedef u16 u16x8 __attribute__((ext_vector_type(8)));
typedef u16 u16x4 __attribute__((ext_vector_type(4)));
typedef u16 u16x2 __attribute__((ext_vector_type(2)));
typedef __bf16 bf16x8 __attribute__((ext_vector_type(8)));
typedef float f32x4 __attribute__((ext_vector_type(4)));

__device__ __forceinline__ float bf2f(u16 u) {
    unsigned int x = ((unsigned int)u) << 16;
    float f; __builtin_memcpy(&f, &x, 4); return f;
}
__device__ __forceinline__ u16 f2bf(float f) {
    unsigned int x; __builtin_memcpy(&x, &f, 4);
    x += 0x7fffu + ((x >> 16) & 1u);   // RNE for finite values
    return (u16)(x >> 16);
}
__device__ __forceinline__ float wsum(float v) {
#pragma unroll
    for (int o = 32; o > 0; o >>= 1) v += __shfl_xor(v, o, 64);
    return v;
}

// ---------------- GEMM: C = A @ B, bf16 MFMA internally ----------------
// A [M,K]: fp32 (A_F32=1) or bf16 (A_F32=0), row-major.
// B [K,N]: fp32 row-major (weights), converted to bf16 in staging.
// C [M,N]: fp32 (C_F32=1) or bf16 (C_F32=0).
#define BM 128
#define BN 128
#define BKK 32
#define SBS (BN + 2)   // padded u16 stride for the [k][n] B tile
template<int A_F32, int C_F32>
__global__ __launch_bounds__(256) void gemm_k(
    const void* __restrict__ Ap, const float* __restrict__ B,
    void* __restrict__ Cp, int M, int N, int K)
{
    __shared__ __align__(16) u16 sA[BM * BKK];   // [m][k], 64B rows
    __shared__ __align__(16) u16 sB[BKK * SBS];  // [k][n], padded
    const int t = threadIdx.x;
    const int lane = t & 63, wave = t >> 6;
    const int m0 = blockIdx.y * BM, n0 = blockIdx.x * BN;
    const int wm = (wave & 1) * 64, wn = (wave >> 1) * 64;
    const int quad = lane >> 4, lr = lane & 15;

    f32x4 acc[4][4] = {};

    for (int kt = 0; kt < K; kt += BKK) {
        // ---- global -> regs (coalesced), convert to bf16 ----
        u16x8 va[2], vb[2];
#pragma unroll
        for (int r = 0; r < 2; ++r) {
            int c = t + r * 256;                    // 0..511
            int arow = c >> 2, aks = (c & 3) * 8;   // A chunk: 8 K-elems
            if (A_F32) {
                const float* ga = (const float*)Ap + (size_t)(m0 + arow) * K + kt + aks;
                f32x4 f0 = *(const f32x4*)ga;
                f32x4 f1 = *(const f32x4*)(ga + 4);
#pragma unroll
                for (int p = 0; p < 4; ++p) { va[r][p] = f2bf(f0[p]); va[r][p + 4] = f2bf(f1[p]); }
            } else {
                va[r] = *(const u16x8*)((const u16*)Ap + (size_t)(m0 + arow) * K + kt + aks);
            }
            int bk = c >> 4, bn = (c & 15) * 8;     // B chunk: 8 N-elems
            const float* gb = B + (size_t)(kt + bk) * N + n0 + bn;
            f32x4 g0 = *(const f32x4*)gb;
            f32x4 g1 = *(const f32x4*)(gb + 4);
#pragma unroll
            for (int p = 0; p < 4; ++p) { vb[r][p] = f2bf(g0[p]); vb[r][p + 4] = f2bf(g1[p]); }
        }
        __syncthreads();   // prior iteration's LDS reads done
        // ---- regs -> LDS ----
#pragma unroll
        for (int r = 0; r < 2; ++r) {
            int c = t + r * 256;
            *(u16x8*)((char*)sA + (size_t)c * 16) = va[r];
            int bk = c >> 4, bn = (c & 15) * 8;
            u16* dst = sB + bk * SBS + bn;          // 4B-aligned
#pragma unroll
            for (int p = 0; p < 4; ++p) {
                u16x2 w; w[0] = vb[r][2 * p]; w[1] = vb[r][2 * p + 1];
                *(u16x2*)(dst + 2 * p) = w;
            }
        }
        __syncthreads();

        // ---- fragments ----
        bf16x8 af[4], bfr[4];
#pragma unroll
        for (int i = 0; i < 4; ++i)
            af[i] = *(const bf16x8*)((const char*)sA + (wm + i * 16 + lr) * 64 + quad * 16);
#pragma unroll
        for (int i = 0; i < 4; ++i) {
            u16 tmp[8];
#pragma unroll
            for (int j = 0; j < 8; ++j)
                tmp[j] = sB[(quad * 8 + j) * SBS + (wn + i * 16 + lr)];
            __builtin_memcpy(&bfr[i], tmp, 16);
        }
#pragma unroll
        for (int i = 0; i < 4; ++i)
#pragma unroll
            for (int j = 0; j < 4; ++j)
                acc[i][j] = __builtin_amdgcn_mfma_f32_16x16x32_bf16(af[i], bfr[j], acc[i][j], 0, 0, 0);
    }
    // epilogue: C/D layout col=lane&15, row=quad*4+r
#pragma unroll
    for (int i = 0; i < 4; ++i) {
        int mrow = m0 + wm + i * 16 + quad * 4;
#pragma unroll
        for (int j = 0; j < 4; ++j) {
            int ncol = n0 + wn + j * 16 + lr;
#pragma unroll
            for (int r = 0; r < 4; ++r) {
                if (C_F32) ((float*)Cp)[(size_t)(mrow + r) * N + ncol] = acc[i][j][r];
                else       ((u16*)Cp)[(size_t)(mrow + r) * N + ncol] = f2bf(acc[i][j][r]);
            }
        }
    }
}

// ---------------- LN1 + hierarchical fusion (wave per row; bf16 y in, bf16 out) ----------------
__global__ __launch_bounds__(256) void ln1_fusion(
    const u16* Y, const float* __restrict__ ltb,
    const float* __restrict__ g1, const float* __restrict__ b1,
    const float* __restrict__ masks, const float* __restrict__ emb,
    u16* fused, int ROWS)
{
    const int lane = threadIdx.x & 63;
    const int wid = blockIdx.x * (blockDim.x >> 6) + (threadIdx.x >> 6);
    const int nw = gridDim.x * (blockDim.x >> 6);
    const int h0 = lane * 16;

    float ltbv[16], gv[16], bv[16], ev[4][16];
#pragma unroll
    for (int i = 0; i < 16; ++i) {
        ltbv[i] = ltb[h0 + i];
        gv[i] = g1[h0 + i];
        bv[i] = b1[h0 + i];
    }
#pragma unroll
    for (int n = 0; n < 4; ++n)
#pragma unroll
        for (int i = 0; i < 16; ++i) ev[n][i] = emb[n * 1024 + h0 + i];

    for (int r = wid; r < ROWS; r += nw) {
        const u16* yrow = Y + (size_t)r * 1024 + h0;
        u16x8 v0 = *(const u16x8*)(yrow);
        u16x8 v1 = *(const u16x8*)(yrow + 8);
        float y[16], s = 0.f, sq = 0.f;
#pragma unroll
        for (int i = 0; i < 8; ++i) { y[i] = bf2f(v0[i]) + ltbv[i]; y[i + 8] = bf2f(v1[i]) + ltbv[i + 8]; }
#pragma unroll
        for (int i = 0; i < 16; ++i) { s += y[i]; sq += y[i] * y[i]; }
        s = wsum(s); sq = wsum(sq);
        float mu = s * (1.f / 1024.f);
        float var = fmaxf(sq * (1.f / 1024.f) - mu * mu, 0.f);
        float rinv = rsqrtf(var + 1e-5f);
        float tv[16];
#pragma unroll
        for (int i = 0; i < 16; ++i) tv[i] = (y[i] - mu) * rinv * gv[i] + bv[i];

        float p0 = 0.f, p1 = 0.f, p2 = 0.f, p3 = 0.f;
#pragma unroll
        for (int i = 0; i < 16; ++i) {
            p0 += tv[i] * ev[0][i]; p1 += tv[i] * ev[1][i];
            p2 += tv[i] * ev[2][i]; p3 += tv[i] * ev[3][i];
        }
        p0 = wsum(p0); p1 = wsum(p1); p2 = wsum(p2); p3 = wsum(p3);
        p0 = fminf(p0, 30.f); p1 = fminf(p1, 30.f); p2 = fminf(p2, 30.f); p3 = fminf(p3, 30.f);

        f32x4 mk = *(const f32x4*)(masks + (size_t)r * 4);
        float w0 = mk[0] > 0.5f ? expf(p0) : 0.f;
        float w1 = mk[1] > 0.5f ? expf(p1) : 0.f;
        float w2 = mk[2] > 0.5f ? expf(p2) : 0.f;
        float w3 = mk[3] > 0.5f ? expf(p3) : 0.f;
        float tot = w0 + w1 + w2 + w3;
        float inv = tot > 1e-8f ? 1.f / tot : 1.f;

        float fu[16], d = 0.f;
#pragma unroll
        for (int i = 0; i < 16; ++i) {
            fu[i] = (w0 * ev[0][i] + w1 * ev[1][i] + w2 * ev[2][i] + w3 * ev[3][i]) * inv;
            d += fu[i] * tv[i];
        }
        d = wsum(d);
        float gate = 1.f / (1.f + expf(fminf(-d * (1.f / 1024.f), 30.f)));

        u16x8 o0, o1;
#pragma unroll
        for (int i = 0; i < 8; ++i) {
            o0[i] = f2bf(gate * fu[i] + (1.f - gate) * tv[i]);
            o1[i] = f2bf(gate * fu[i + 8] + (1.f - gate) * tv[i + 8]);
        }
        u16* orow = fused + (size_t)r * 1024 + h0;
        *(u16x8*)(orow) = o0;
        *(u16x8*)(orow + 8) = o1;
    }
}

// ---------------- multi-scale windowed means (bf16 -> bf16) ----------------
__global__ __launch_bounds__(256) void multiscale(
    const u16* __restrict__ fused, u16* __restrict__ agg, int L)
{
    const int bl = blockIdx.x;        // b*L + l
    const int b = bl / L, l = bl - b * L;
    const int h0 = threadIdx.x * 4;

    const float sw[4] = { 1.f, 1.f / (1.f + logf(3.f)), 1.f / (1.f + logf(7.f)), 1.f / (1.f + logf(15.f)) };
    const int half[4] = { 0, 1, 3, 7 };
    float coef[4];
#pragma unroll
    for (int s = 0; s < 4; ++s) {
        int st = l - half[s]; if (st < 0) st = 0;
        int en = l + half[s] + 1; if (en > L) en = L;
        coef[s] = sw[s] / (float)(en - st);
    }
    float a0 = 0.f, a1 = 0.f, a2 = 0.f, a3 = 0.f;
#pragma unroll
    for (int d = -7; d <= 7; ++d) {
        int j = l + d;
        if ((unsigned)j >= (unsigned)L) continue;
        int ad = d < 0 ? -d : d;
        float c = coef[3];
        if (ad <= 3) c += coef[2];
        if (ad <= 1) c += coef[1];
        if (ad == 0) c += coef[0];
        u16x4 v = *(const u16x4*)(fused + ((size_t)(b * L + j)) * 1024 + h0);
        a0 += c * bf2f(v[0]); a1 += c * bf2f(v[1]);
        a2 += c * bf2f(v[2]); a3 += c * bf2f(v[3]);
    }
    u16x4 o; o[0] = f2bf(a0); o[1] = f2bf(a1); o[2] = f2bf(a2); o[3] = f2bf(a3);
    *(u16x4*)(agg + (size_t)bl * 1024 + h0) = o;
}

// ---------------- LN2 + residual, fp32 in-place on d_out ----------------
__global__ __launch_bounds__(256) void ln2_res(
    float* Y, const float* __restrict__ ftb,
    const float* __restrict__ g2, const float* __restrict__ b2,
    const float* __restrict__ x, int ROWS)
{
    const int lane = threadIdx.x & 63;
    const int wid = blockIdx.x * (blockDim.x >> 6) + (threadIdx.x >> 6);
    const int nw = gridDim.x * (blockDim.x >> 6);
    const int h0 = lane * 16;

    float ftbv[16], gv[16], bv[16];
#pragma unroll
    for (int i = 0; i < 16; ++i) {
        ftbv[i] = ftb[h0 + i];
        gv[i] = g2[h0 + i];
        bv[i] = b2[h0 + i];
    }
    for (int r = wid; r < ROWS; r += nw) {
        float* yrow = Y + (size_t)r * 1024 + h0;
        float y[16], s = 0.f, sq = 0.f;
#pragma unroll
        for (int q = 0; q < 4; ++q) {
            f32x4 v = *(const f32x4*)(yrow + 4 * q);
#pragma unroll
            for (int p = 0; p < 4; ++p) y[4 * q + p] = v[p] + ftbv[4 * q + p];
        }
#pragma unroll
        for (int i = 0; i < 16; ++i) { s += y[i]; sq += y[i] * y[i]; }
        s = wsum(s); sq = wsum(sq);
        float mu = s * (1.f / 1024.f);
        float var = fmaxf(sq * (1.f / 1024.f) - mu * mu, 0.f);
        float rinv = rsqrtf(var + 1e-5f);

        const float* xrow = x + (size_t)r * 1024 + h0;
#pragma unroll
        for (int q = 0; q < 4; ++q) {
            f32x4 xv = *(const f32x4*)(xrow + 4 * q);
            f32x4 o;
#pragma unroll
            for (int p = 0; p < 4; ++p)
                o[p] = (y[4 * q + p] - mu) * rinv * gv[4 * q + p] + bv[4 * q + p] + xv[p];
            *(f32x4*)(yrow + 4 * q) = o;
        }
    }
}

extern "C" void kernel_launch(void* const* d_in, const int* in_sizes, int n_in,
                              void* d_out, int out_size, void* d_ws, size_t ws_size,
                              hipStream_t stream) {
    const float* x     = (const float*)d_in[0];   // [B,L,H] fp32
    const float* masks = (const float*)d_in[1];   // [B,L,4] fp32
    const float* emb   = (const float*)d_in[2];   // [4,H]   fp32
    const float* ltw   = (const float*)d_in[3];   // [H,H]   fp32
    const float* ltb   = (const float*)d_in[4];
    const float* g1    = (const float*)d_in[5];
    const float* b1    = (const float*)d_in[6];
    const float* ftw   = (const float*)d_in[7];   // [H,H]   fp32
    const float* ftb   = (const float*)d_in[8];
    const float* g2    = (const float*)d_in[9];
    const float* b2    = (const float*)d_in[10];
    float* out = (float*)d_out;                   // [B,L,H] fp32 (128 MB)

    const int H = 1024, L = 4096;
    const int M = in_sizes[0] / H;                // B*L = 32768

    u16* plane0 = (u16*)d_out;   // lower 64 MB of d_out: bf16 y1 / fused (dead before fp32 C-write)
    u16* aggP   = (u16*)d_ws;    // 64 MB bf16 agg plane (only ws use)

    gemm_k<1, 0><<<dim3(H / BN, M / BM), 256, 0, stream>>>(x, ltw, plane0, M, H, H);      // y1 bf16 -> plane0
    ln1_fusion<<<1024, 256, 0, stream>>>(plane0, ltb, g1, b1, masks, emb, plane0, M);     // fused in-place
    multiscale<<<M, 256, 0, stream>>>(plane0, aggP, L);                                   // agg bf16 -> ws
    gemm_k<0, 1><<<dim3(H / BN, M / BM), 256, 0, stream>>>(aggP, ftw, out, M, H, H);      // y2 fp32 -> d_out
    ln2_res<<<1024, 256, 0, stream>>>(out, ftb, g2, b2, x, M);                            // LN2 + residual in-place
}